// Round 6
// baseline (211.651 us; speedup 1.0000x reference)
//
#include <hip/hip_runtime.h>
#include <hip/hip_bf16.h>

// ---------------------------------------------------------------------------
// GCN layer: out = relu(segment_sum(adj_vals * (x@W)[cols], rows))
//   x: [50000,256] f32, W: [256,128] f32, edges: 800000
// Stage 1: register-tiled GEMM support = x @ W
//          64x128 tile, per-thread 8x4; register double-buffered staging so
//          global-load latency overlaps the FMA phase (one LDS buffer).
// Stage 2: CSR build: hist -> 3-pass multiblock scan -> fill into interleaved
//          (col,val) int2 array (atomics convert offsets to end-pointers)
// Stage 3: per-node gather-accumulate + ReLU    (atomic-free, fused)
// Fallback (ws too small): atomicAdd scatter path.
// ---------------------------------------------------------------------------

#define IN_F  256
#define OUT_F 128

#define BM 64
#define BN 128
#define BK 32
#define XPAD 68   // 68*4B per row: keeps float4 alignment of xs_t[kk]

// ---------------------------- Stage 1: GEMM -------------------------------
__global__ __launch_bounds__(256) void gcn_gemm_kernel(
    const float* __restrict__ x, const float* __restrict__ w,
    float* __restrict__ support, int n_nodes)
{
    __shared__ float xs_t[BK][XPAD];   // transposed x tile: [kk][row], 8.7 KB
    __shared__ float ws_[BK][BN];      // w tile: 16 KB

    const int tid  = threadIdx.x;
    const int cg   = tid & 31;         // float4 col chunk: cols cg*4..cg*4+3
    const int rg   = tid >> 5;         // row group 0..7: rows rg*4.. and rg*4+32..
    const int row0 = blockIdx.x * BM;

    float acc[8][4];
#pragma unroll
    for (int i = 0; i < 8; ++i)
#pragma unroll
        for (int j = 0; j < 4; ++j) acc[i][j] = 0.f;

    float4 xr[2];   // register prefetch: x tile (2 float4/thread)
    float4 wr[4];   // register prefetch: w tile (4 float4/thread)

    // prefetch tile 0
#pragma unroll
    for (int i = 0; i < 2; ++i) {
        int t   = tid + i * 256;
        int r   = t >> 3;
        int kk  = (t & 7) << 2;
        int row = row0 + r;
        xr[i] = make_float4(0.f, 0.f, 0.f, 0.f);
        if (row < n_nodes)
            xr[i] = *reinterpret_cast<const float4*>(&x[(size_t)row * IN_F + kk]);
    }
#pragma unroll
    for (int i = 0; i < 4; ++i) {
        int fi = tid + i * 256;
        int kk = fi >> 5;
        int cc = (fi & 31) << 2;
        wr[i] = *reinterpret_cast<const float4*>(&w[(size_t)kk * OUT_F + cc]);
    }

    for (int k0 = 0; k0 < IN_F; k0 += BK) {
        if (k0 > 0) __syncthreads();   // previous tile's readers done
        // regs -> LDS
#pragma unroll
        for (int i = 0; i < 2; ++i) {
            int t  = tid + i * 256;
            int r  = t >> 3;
            int kk = (t & 7) << 2;
            xs_t[kk + 0][r] = xr[i].x;
            xs_t[kk + 1][r] = xr[i].y;
            xs_t[kk + 2][r] = xr[i].z;
            xs_t[kk + 3][r] = xr[i].w;
        }
#pragma unroll
        for (int i = 0; i < 4; ++i) {
            int fi = tid + i * 256;
            int kk = fi >> 5;
            int cc = (fi & 31) << 2;
            *reinterpret_cast<float4*>(&ws_[kk][cc]) = wr[i];
        }
        __syncthreads();

        // issue next tile's loads; latency hides under the FMA phase below
        if (k0 + BK < IN_F) {
#pragma unroll
            for (int i = 0; i < 2; ++i) {
                int t   = tid + i * 256;
                int r   = t >> 3;
                int kk  = (t & 7) << 2;
                int row = row0 + r;
                xr[i] = make_float4(0.f, 0.f, 0.f, 0.f);
                if (row < n_nodes)
                    xr[i] = *reinterpret_cast<const float4*>(
                        &x[(size_t)row * IN_F + k0 + BK + kk]);
            }
#pragma unroll
            for (int i = 0; i < 4; ++i) {
                int fi = tid + i * 256;
                int kk = fi >> 5;
                int cc = (fi & 31) << 2;
                wr[i] = *reinterpret_cast<const float4*>(
                    &w[(size_t)(k0 + BK + kk) * OUT_F + cc]);
            }
        }

#pragma unroll
        for (int kk = 0; kk < BK; ++kk) {
            // broadcast reads (2 addresses per wave each) — conflict-free
            float4 a0 = *reinterpret_cast<const float4*>(&xs_t[kk][rg * 4]);
            float4 a1 = *reinterpret_cast<const float4*>(&xs_t[kk][rg * 4 + 32]);
            // contiguous b128 across wave
            float4 b  = *reinterpret_cast<const float4*>(&ws_[kk][cg * 4]);
            const float av[8] = {a0.x, a0.y, a0.z, a0.w, a1.x, a1.y, a1.z, a1.w};
            const float bv[4] = {b.x, b.y, b.z, b.w};
#pragma unroll
            for (int i = 0; i < 8; ++i)
#pragma unroll
                for (int j = 0; j < 4; ++j)
                    acc[i][j] += av[i] * bv[j];
        }
    }

#pragma unroll
    for (int i = 0; i < 8; ++i) {
        int row = row0 + rg * 4 + (i & 3) + (i >> 2) * 32;
        if (row < n_nodes) {
            float4 o = make_float4(acc[i][0], acc[i][1], acc[i][2], acc[i][3]);
            *reinterpret_cast<float4*>(&support[(size_t)row * OUT_F + cg * 4]) = o;
        }
    }
}

// ------------------------- Stage 2: CSR build ------------------------------
__global__ __launch_bounds__(256) void gcn_hist_kernel(
    const int* __restrict__ rows, int* __restrict__ deg, int n_edges)
{
    int e = blockIdx.x * blockDim.x + threadIdx.x;
    if (e < n_edges) atomicAdd(&deg[rows[e]], 1);
}

// --- multi-block exclusive scan: pass 1 (block-local scan + block sums) ----
__global__ __launch_bounds__(256) void gcn_scan1_kernel(
    const int* __restrict__ deg, int* __restrict__ offsets,
    int* __restrict__ block_sums, int n)
{
    __shared__ int part[256];
    const int tid  = threadIdx.x;
    const int base = blockIdx.x * 1024 + tid * 4;

    int4 v = make_int4(0, 0, 0, 0);
    if (base + 3 < n) {
        v = *reinterpret_cast<const int4*>(&deg[base]);
    } else {
        if (base + 0 < n) v.x = deg[base + 0];
        if (base + 1 < n) v.y = deg[base + 1];
        if (base + 2 < n) v.z = deg[base + 2];
        if (base + 3 < n) v.w = deg[base + 3];
    }
    int s = v.x + v.y + v.z + v.w;
    part[tid] = s;
    __syncthreads();
    for (int d = 1; d < 256; d <<= 1) {
        int t = (tid >= d) ? part[tid - d] : 0;
        __syncthreads();
        part[tid] += t;
        __syncthreads();
    }
    int ex = part[tid] - s;
    int4 o;
    o.x = ex;
    o.y = o.x + v.x;
    o.z = o.y + v.y;
    o.w = o.z + v.z;
    if (base + 3 < n) {
        *reinterpret_cast<int4*>(&offsets[base]) = o;
    } else {
        if (base + 0 < n) offsets[base + 0] = o.x;
        if (base + 1 < n) offsets[base + 1] = o.y;
        if (base + 2 < n) offsets[base + 2] = o.z;
        if (base + 3 < n) offsets[base + 3] = o.w;
    }
    if (tid == 255) block_sums[blockIdx.x] = part[255];
}

__global__ __launch_bounds__(256) void gcn_scan2_kernel(
    int* __restrict__ block_sums, int nb)
{
    __shared__ int part[256];
    const int tid = threadIdx.x;
    int s = (tid < nb) ? block_sums[tid] : 0;
    part[tid] = s;
    __syncthreads();
    for (int d = 1; d < 256; d <<= 1) {
        int t = (tid >= d) ? part[tid - d] : 0;
        __syncthreads();
        part[tid] += t;
        __syncthreads();
    }
    if (tid < nb) block_sums[tid] = part[tid] - s;
}

__global__ __launch_bounds__(256) void gcn_scan3_kernel(
    int* __restrict__ offsets, const int* __restrict__ block_sums, int n)
{
    const int base = blockIdx.x * 1024 + threadIdx.x * 4;
    const int add  = block_sums[blockIdx.x];
    if (base + 3 < n) {
        int4 v = *reinterpret_cast<const int4*>(&offsets[base]);
        v.x += add; v.y += add; v.z += add; v.w += add;
        *reinterpret_cast<int4*>(&offsets[base]) = v;
    } else {
        if (base + 0 < n) offsets[base + 0] += add;
        if (base + 1 < n) offsets[base + 1] += add;
        if (base + 2 < n) offsets[base + 2] += add;
        if (base + 3 < n) offsets[base + 3] += add;
    }
}

// --- fill: one interleaved 8B (col,val) store per edge ---------------------
__global__ __launch_bounds__(256) void gcn_fill_kernel(
    const int* __restrict__ rows, const int* __restrict__ cols,
    const float* __restrict__ vals, int* __restrict__ offsets,
    int2* __restrict__ csr_cv, int n_edges)
{
    int e = blockIdx.x * blockDim.x + threadIdx.x;
    if (e >= n_edges) return;
    int r = rows[e];
    int pos = atomicAdd(&offsets[r], 1);
    int2 cv;
    cv.x = cols[e];
    cv.y = __float_as_int(vals[e]);
    csr_cv[pos] = cv;
}

// ---------------- Stage 3: per-node accumulate + ReLU ----------------------
// after fill, offsets[r] is the END pointer of row r; start = offsets[r-1]
__global__ __launch_bounds__(256) void gcn_gather_kernel(
    const float* __restrict__ support, const int* __restrict__ offsets,
    const int2* __restrict__ csr_cv, float* __restrict__ out, int n_nodes)
{
    const int node = blockIdx.x * 4 + (threadIdx.x >> 6);
    const int lane = threadIdx.x & 63;
    if (node >= n_nodes) return;

    const int end   = offsets[node];
    const int start = (node == 0) ? 0 : offsets[node - 1];
    const int d     = end - start;
    const int off   = start;

    float2 acc = make_float2(0.f, 0.f);
    int j = 0;
    for (; j + 3 < d; j += 4) {
        int2 cv0 = csr_cv[off + j];
        int2 cv1 = csr_cv[off + j + 1];
        int2 cv2 = csr_cv[off + j + 2];
        int2 cv3 = csr_cv[off + j + 3];
        float v0 = __int_as_float(cv0.y);
        float v1 = __int_as_float(cv1.y);
        float v2 = __int_as_float(cv2.y);
        float v3 = __int_as_float(cv3.y);
        float2 s0 = *reinterpret_cast<const float2*>(&support[(size_t)cv0.x * OUT_F + lane * 2]);
        float2 s1 = *reinterpret_cast<const float2*>(&support[(size_t)cv1.x * OUT_F + lane * 2]);
        float2 s2 = *reinterpret_cast<const float2*>(&support[(size_t)cv2.x * OUT_F + lane * 2]);
        float2 s3 = *reinterpret_cast<const float2*>(&support[(size_t)cv3.x * OUT_F + lane * 2]);
        acc.x += v0 * s0.x + v1 * s1.x + v2 * s2.x + v3 * s3.x;
        acc.y += v0 * s0.y + v1 * s1.y + v2 * s2.y + v3 * s3.y;
    }
    for (; j < d; ++j) {
        int2 cv0 = csr_cv[off + j];
        float v0 = __int_as_float(cv0.y);
        float2 s0 = *reinterpret_cast<const float2*>(&support[(size_t)cv0.x * OUT_F + lane * 2]);
        acc.x += v0 * s0.x;
        acc.y += v0 * s0.y;
    }

    float2 o;
    o.x = fmaxf(acc.x, 0.f);
    o.y = fmaxf(acc.y, 0.f);
    *reinterpret_cast<float2*>(&out[(size_t)node * OUT_F + lane * 2]) = o;
}

// ------------------------- Fallback (atomic) -------------------------------
__global__ __launch_bounds__(256) void gcn_scatter_kernel(
    const float* __restrict__ support, const float* __restrict__ vals,
    const int* __restrict__ rows, const int* __restrict__ cols,
    float* __restrict__ out, int n_edges)
{
    long long idx   = (long long)blockIdx.x * blockDim.x + threadIdx.x;
    long long total = (long long)n_edges * (OUT_F / 4);
    if (idx >= total) return;

    int e  = (int)(idx >> 5);
    int f4 = (int)(idx & 31);
    int r  = rows[e];
    int c  = cols[e];
    float v = vals[e];

    float4 s = *reinterpret_cast<const float4*>(&support[(size_t)c * OUT_F + f4 * 4]);
    float* o = &out[(size_t)r * OUT_F + f4 * 4];
    atomicAdd(o + 0, v * s.x);
    atomicAdd(o + 1, v * s.y);
    atomicAdd(o + 2, v * s.z);
    atomicAdd(o + 3, v * s.w);
}

__global__ __launch_bounds__(256) void gcn_relu_kernel(float* __restrict__ out, int n4)
{
    int idx = blockIdx.x * blockDim.x + threadIdx.x;
    if (idx >= n4) return;
    float4* p = reinterpret_cast<float4*>(out) + idx;
    float4 v = *p;
    v.x = fmaxf(v.x, 0.f);
    v.y = fmaxf(v.y, 0.f);
    v.z = fmaxf(v.z, 0.f);
    v.w = fmaxf(v.w, 0.f);
    *p = v;
}

// ---------------------------------------------------------------------------
static inline char* align16(char* p) {
    return (char*)(((uintptr_t)p + 15) & ~(uintptr_t)15);
}

extern "C" void kernel_launch(void* const* d_in, const int* in_sizes, int n_in,
                              void* d_out, int out_size, void* d_ws, size_t ws_size,
                              hipStream_t stream)
{
    const float* x    = (const float*)d_in[0];
    const float* w    = (const float*)d_in[1];
    const float* vals = (const float*)d_in[2];
    const int*   rows = (const int*)d_in[3];
    const int*   cols = (const int*)d_in[4];
    float* out = (float*)d_out;

    const int n_nodes = in_sizes[0] / IN_F;     // 50000
    const int n_edges = in_sizes[2];            // 800000

    const int scan_blocks = (n_nodes + 1023) / 1024;   // 49 for n=50000

    // workspace layout (16B-aligned slots)
    char* p = (char*)d_ws;
    float* support = (float*)p;  p = align16(p + (size_t)n_nodes * OUT_F * sizeof(float));
    int*   offsets = (int*)p;    p = align16(p + (size_t)n_nodes * sizeof(int));
    int*   deg     = (int*)p;    p = align16(p + (size_t)n_nodes * sizeof(int));
    int*   bsums   = (int*)p;    p = align16(p + (size_t)256 * sizeof(int));
    int2*  csr_cv  = (int2*)p;   p = align16(p + (size_t)n_edges * sizeof(int2));
    size_t needed = (size_t)(p - (char*)d_ws);

    // Stage 1: GEMM (both paths need it)
    int gemm_blocks = (n_nodes + BM - 1) / BM;
    gcn_gemm_kernel<<<gemm_blocks, 256, 0, stream>>>(x, w, support, n_nodes);

    const int eb = (n_edges + 255) / 256;

    if (ws_size >= needed && scan_blocks <= 256) {
        // Stage 2: CSR build
        hipMemsetAsync(deg, 0, (size_t)n_nodes * sizeof(int), stream);
        gcn_hist_kernel<<<eb, 256, 0, stream>>>(rows, deg, n_edges);
        gcn_scan1_kernel<<<scan_blocks, 256, 0, stream>>>(deg, offsets, bsums, n_nodes);
        gcn_scan2_kernel<<<1, 256, 0, stream>>>(bsums, scan_blocks);
        gcn_scan3_kernel<<<scan_blocks, 256, 0, stream>>>(offsets, bsums, n_nodes);
        gcn_fill_kernel<<<eb, 256, 0, stream>>>(rows, cols, vals, offsets,
                                                csr_cv, n_edges);
        // Stage 3: atomic-free accumulate + fused ReLU
        int gb = (n_nodes + 3) / 4;
        gcn_gather_kernel<<<gb, 256, 0, stream>>>(support, offsets,
                                                  csr_cv, out, n_nodes);
    } else {
        // fallback: proven atomic path
        hipMemsetAsync(d_out, 0, (size_t)out_size * sizeof(float), stream);
        long long total = (long long)n_edges * (OUT_F / 4);
        int sc_blocks = (int)((total + 255) / 256);
        gcn_scatter_kernel<<<sc_blocks, 256, 0, stream>>>(support, vals, rows, cols,
                                                          out, n_edges);
        int n4 = out_size / 4;
        gcn_relu_kernel<<<(n4 + 255) / 256, 256, 0, stream>>>(out, n4);
    }
}

// Round 7
// 210.454 us; speedup vs baseline: 1.0057x; 1.0057x over previous
//
#include <hip/hip_runtime.h>
#include <hip/hip_bf16.h>

// ---------------------------------------------------------------------------
// GCN layer: out = relu(segment_sum(adj_vals * (x@W)[cols], rows))
//   x: [50000,256] f32, W: [256,128] f32, edges: 800000
// Stage 1: register-tiled GEMM support = x @ W
//          64x128 tile, BK=64 (4 K-steps, halved barrier drains),
//          W tile staged via global_load_lds (16B, no VGPR roundtrip),
//          x tile register-staged + transposed into LDS.
// Stage 2: CSR build: hist -> 3-pass multiblock scan -> fill into interleaved
//          (col,val) int2 array (atomics convert offsets to end-pointers)
// Stage 3: per-node gather-accumulate + ReLU    (atomic-free, fused)
// Fallback (ws too small): atomicAdd scatter path.
// ---------------------------------------------------------------------------

#define IN_F  256
#define OUT_F 128

#define BM 64
#define BN 128
#define BK 64
#define XPAD 68   // 68*4B per row: keeps float4 alignment of xs_t[kk]

// ---------------------------- Stage 1: GEMM -------------------------------
__global__ __launch_bounds__(256) void gcn_gemm_kernel(
    const float* __restrict__ x, const float* __restrict__ w,
    float* __restrict__ support, int n_nodes)
{
    __shared__ float xs_t[BK][XPAD];   // transposed x tile: [kk][row], 17.4 KB
    __shared__ float ws_[BK][BN];      // w tile: 32 KB

    const int tid  = threadIdx.x;
    const int cg   = tid & 31;         // float4 col chunk: cols cg*4..cg*4+3
    const int rg   = tid >> 5;         // row group 0..7: rows rg*4.. and rg*4+32..
    const int row0 = blockIdx.x * BM;

    float acc[8][4];
#pragma unroll
    for (int i = 0; i < 8; ++i)
#pragma unroll
        for (int j = 0; j < 4; ++j) acc[i][j] = 0.f;

    for (int k0 = 0; k0 < IN_F; k0 += BK) {
        if (k0 > 0) __syncthreads();   // previous tile's readers done

        // --- W tile: rows k0..k0+63 x all 128 cols = contiguous 32 KB ---
        // global_load_lds: LDS dst is wave-uniform base + lane*16 (linear),
        // 8 x 16B per thread. No VGPR roundtrip.
        {
            const char* wsrc = (const char*)w + (size_t)k0 * BN * sizeof(float);
#pragma unroll
            for (int i = 0; i < 8; ++i) {
                int fi = tid + i * 256;              // float4 index 0..2047
                __builtin_amdgcn_global_load_lds(
                    (const __attribute__((address_space(1))) uint32_t*)(wsrc + (size_t)fi * 16),
                    (__attribute__((address_space(3))) uint32_t*)((char*)&ws_[0][0] + (size_t)fi * 16),
                    16, 0, 0);
            }
        }

        // --- x tile: 64 rows x 64 k, 4 float4/thread, stored transposed ---
        float4 xr[4];
#pragma unroll
        for (int i = 0; i < 4; ++i) {
            int t   = tid + i * 256;         // 0..1023
            int r   = t >> 4;                // 0..63
            int kk  = (t & 15) << 2;         // 0,4,..,60
            int row = row0 + r;
            xr[i] = make_float4(0.f, 0.f, 0.f, 0.f);
            if (row < n_nodes)
                xr[i] = *reinterpret_cast<const float4*>(&x[(size_t)row * IN_F + k0 + kk]);
        }
#pragma unroll
        for (int i = 0; i < 4; ++i) {
            int t  = tid + i * 256;
            int r  = t >> 4;
            int kk = (t & 15) << 2;
            xs_t[kk + 0][r] = xr[i].x;
            xs_t[kk + 1][r] = xr[i].y;
            xs_t[kk + 2][r] = xr[i].z;
            xs_t[kk + 3][r] = xr[i].w;
        }
        __syncthreads();   // drains vmcnt (W in LDS) + lgkm (x writes)

#pragma unroll
        for (int kk = 0; kk < BK; ++kk) {
            // broadcast reads (2 addresses per wave each) — conflict-free
            float4 a0 = *reinterpret_cast<const float4*>(&xs_t[kk][rg * 4]);
            float4 a1 = *reinterpret_cast<const float4*>(&xs_t[kk][rg * 4 + 32]);
            // contiguous b128 across wave
            float4 b  = *reinterpret_cast<const float4*>(&ws_[kk][cg * 4]);
            const float av[8] = {a0.x, a0.y, a0.z, a0.w, a1.x, a1.y, a1.z, a1.w};
            const float bv[4] = {b.x, b.y, b.z, b.w};
#pragma unroll
            for (int i = 0; i < 8; ++i)
#pragma unroll
                for (int j = 0; j < 4; ++j)
                    acc[i][j] += av[i] * bv[j];
        }
    }

#pragma unroll
    for (int i = 0; i < 8; ++i) {
        int row = row0 + rg * 4 + (i & 3) + (i >> 2) * 32;
        if (row < n_nodes) {
            float4 o = make_float4(acc[i][0], acc[i][1], acc[i][2], acc[i][3]);
            *reinterpret_cast<float4*>(&support[(size_t)row * OUT_F + cg * 4]) = o;
        }
    }
}

// ------------------------- Stage 2: CSR build ------------------------------
__global__ __launch_bounds__(256) void gcn_hist_kernel(
    const int* __restrict__ rows, int* __restrict__ deg, int n_edges)
{
    int e = blockIdx.x * blockDim.x + threadIdx.x;
    if (e < n_edges) atomicAdd(&deg[rows[e]], 1);
}

// --- multi-block exclusive scan: pass 1 (block-local scan + block sums) ----
__global__ __launch_bounds__(256) void gcn_scan1_kernel(
    const int* __restrict__ deg, int* __restrict__ offsets,
    int* __restrict__ block_sums, int n)
{
    __shared__ int part[256];
    const int tid  = threadIdx.x;
    const int base = blockIdx.x * 1024 + tid * 4;

    int4 v = make_int4(0, 0, 0, 0);
    if (base + 3 < n) {
        v = *reinterpret_cast<const int4*>(&deg[base]);
    } else {
        if (base + 0 < n) v.x = deg[base + 0];
        if (base + 1 < n) v.y = deg[base + 1];
        if (base + 2 < n) v.z = deg[base + 2];
        if (base + 3 < n) v.w = deg[base + 3];
    }
    int s = v.x + v.y + v.z + v.w;
    part[tid] = s;
    __syncthreads();
    for (int d = 1; d < 256; d <<= 1) {
        int t = (tid >= d) ? part[tid - d] : 0;
        __syncthreads();
        part[tid] += t;
        __syncthreads();
    }
    int ex = part[tid] - s;
    int4 o;
    o.x = ex;
    o.y = o.x + v.x;
    o.z = o.y + v.y;
    o.w = o.z + v.z;
    if (base + 3 < n) {
        *reinterpret_cast<int4*>(&offsets[base]) = o;
    } else {
        if (base + 0 < n) offsets[base + 0] = o.x;
        if (base + 1 < n) offsets[base + 1] = o.y;
        if (base + 2 < n) offsets[base + 2] = o.z;
        if (base + 3 < n) offsets[base + 3] = o.w;
    }
    if (tid == 255) block_sums[blockIdx.x] = part[255];
}

__global__ __launch_bounds__(256) void gcn_scan2_kernel(
    int* __restrict__ block_sums, int nb)
{
    __shared__ int part[256];
    const int tid = threadIdx.x;
    int s = (tid < nb) ? block_sums[tid] : 0;
    part[tid] = s;
    __syncthreads();
    for (int d = 1; d < 256; d <<= 1) {
        int t = (tid >= d) ? part[tid - d] : 0;
        __syncthreads();
        part[tid] += t;
        __syncthreads();
    }
    if (tid < nb) block_sums[tid] = part[tid] - s;
}

__global__ __launch_bounds__(256) void gcn_scan3_kernel(
    int* __restrict__ offsets, const int* __restrict__ block_sums, int n)
{
    const int base = blockIdx.x * 1024 + threadIdx.x * 4;
    const int add  = block_sums[blockIdx.x];
    if (base + 3 < n) {
        int4 v = *reinterpret_cast<const int4*>(&offsets[base]);
        v.x += add; v.y += add; v.z += add; v.w += add;
        *reinterpret_cast<int4*>(&offsets[base]) = v;
    } else {
        if (base + 0 < n) offsets[base + 0] += add;
        if (base + 1 < n) offsets[base + 1] += add;
        if (base + 2 < n) offsets[base + 2] += add;
        if (base + 3 < n) offsets[base + 3] += add;
    }
}

// --- fill: one interleaved 8B (col,val) store per edge ---------------------
__global__ __launch_bounds__(256) void gcn_fill_kernel(
    const int* __restrict__ rows, const int* __restrict__ cols,
    const float* __restrict__ vals, int* __restrict__ offsets,
    int2* __restrict__ csr_cv, int n_edges)
{
    int e = blockIdx.x * blockDim.x + threadIdx.x;
    if (e >= n_edges) return;
    int r = rows[e];
    int pos = atomicAdd(&offsets[r], 1);
    int2 cv;
    cv.x = cols[e];
    cv.y = __float_as_int(vals[e]);
    csr_cv[pos] = cv;
}

// ---------------- Stage 3: per-node accumulate + ReLU ----------------------
// after fill, offsets[r] is the END pointer of row r; start = offsets[r-1]
__global__ __launch_bounds__(256) void gcn_gather_kernel(
    const float* __restrict__ support, const int* __restrict__ offsets,
    const int2* __restrict__ csr_cv, float* __restrict__ out, int n_nodes)
{
    const int node = blockIdx.x * 4 + (threadIdx.x >> 6);
    const int lane = threadIdx.x & 63;
    if (node >= n_nodes) return;

    const int end   = offsets[node];
    const int start = (node == 0) ? 0 : offsets[node - 1];
    const int d     = end - start;
    const int off   = start;

    float2 acc = make_float2(0.f, 0.f);
    int j = 0;
    for (; j + 3 < d; j += 4) {
        int2 cv0 = csr_cv[off + j];
        int2 cv1 = csr_cv[off + j + 1];
        int2 cv2 = csr_cv[off + j + 2];
        int2 cv3 = csr_cv[off + j + 3];
        float v0 = __int_as_float(cv0.y);
        float v1 = __int_as_float(cv1.y);
        float v2 = __int_as_float(cv2.y);
        float v3 = __int_as_float(cv3.y);
        float2 s0 = *reinterpret_cast<const float2*>(&support[(size_t)cv0.x * OUT_F + lane * 2]);
        float2 s1 = *reinterpret_cast<const float2*>(&support[(size_t)cv1.x * OUT_F + lane * 2]);
        float2 s2 = *reinterpret_cast<const float2*>(&support[(size_t)cv2.x * OUT_F + lane * 2]);
        float2 s3 = *reinterpret_cast<const float2*>(&support[(size_t)cv3.x * OUT_F + lane * 2]);
        acc.x += v0 * s0.x + v1 * s1.x + v2 * s2.x + v3 * s3.x;
        acc.y += v0 * s0.y + v1 * s1.y + v2 * s2.y + v3 * s3.y;
    }
    for (; j < d; ++j) {
        int2 cv0 = csr_cv[off + j];
        float v0 = __int_as_float(cv0.y);
        float2 s0 = *reinterpret_cast<const float2*>(&support[(size_t)cv0.x * OUT_F + lane * 2]);
        acc.x += v0 * s0.x;
        acc.y += v0 * s0.y;
    }

    float2 o;
    o.x = fmaxf(acc.x, 0.f);
    o.y = fmaxf(acc.y, 0.f);
    *reinterpret_cast<float2*>(&out[(size_t)node * OUT_F + lane * 2]) = o;
}

// ------------------------- Fallback (atomic) -------------------------------
__global__ __launch_bounds__(256) void gcn_scatter_kernel(
    const float* __restrict__ support, const float* __restrict__ vals,
    const int* __restrict__ rows, const int* __restrict__ cols,
    float* __restrict__ out, int n_edges)
{
    long long idx   = (long long)blockIdx.x * blockDim.x + threadIdx.x;
    long long total = (long long)n_edges * (OUT_F / 4);
    if (idx >= total) return;

    int e  = (int)(idx >> 5);
    int f4 = (int)(idx & 31);
    int r  = rows[e];
    int c  = cols[e];
    float v = vals[e];

    float4 s = *reinterpret_cast<const float4*>(&support[(size_t)c * OUT_F + f4 * 4]);
    float* o = &out[(size_t)r * OUT_F + f4 * 4];
    atomicAdd(o + 0, v * s.x);
    atomicAdd(o + 1, v * s.y);
    atomicAdd(o + 2, v * s.z);
    atomicAdd(o + 3, v * s.w);
}

__global__ __launch_bounds__(256) void gcn_relu_kernel(float* __restrict__ out, int n4)
{
    int idx = blockIdx.x * blockDim.x + threadIdx.x;
    if (idx >= n4) return;
    float4* p = reinterpret_cast<float4*>(out) + idx;
    float4 v = *p;
    v.x = fmaxf(v.x, 0.f);
    v.y = fmaxf(v.y, 0.f);
    v.z = fmaxf(v.z, 0.f);
    v.w = fmaxf(v.w, 0.f);
    *p = v;
}

// ---------------------------------------------------------------------------
static inline char* align16(char* p) {
    return (char*)(((uintptr_t)p + 15) & ~(uintptr_t)15);
}

extern "C" void kernel_launch(void* const* d_in, const int* in_sizes, int n_in,
                              void* d_out, int out_size, void* d_ws, size_t ws_size,
                              hipStream_t stream)
{
    const float* x    = (const float*)d_in[0];
    const float* w    = (const float*)d_in[1];
    const float* vals = (const float*)d_in[2];
    const int*   rows = (const int*)d_in[3];
    const int*   cols = (const int*)d_in[4];
    float* out = (float*)d_out;

    const int n_nodes = in_sizes[0] / IN_F;     // 50000
    const int n_edges = in_sizes[2];            // 800000

    const int scan_blocks = (n_nodes + 1023) / 1024;   // 49 for n=50000

    // workspace layout (16B-aligned slots)
    char* p = (char*)d_ws;
    float* support = (float*)p;  p = align16(p + (size_t)n_nodes * OUT_F * sizeof(float));
    int*   offsets = (int*)p;    p = align16(p + (size_t)n_nodes * sizeof(int));
    int*   deg     = (int*)p;    p = align16(p + (size_t)n_nodes * sizeof(int));
    int*   bsums   = (int*)p;    p = align16(p + (size_t)256 * sizeof(int));
    int2*  csr_cv  = (int2*)p;   p = align16(p + (size_t)n_edges * sizeof(int2));
    size_t needed = (size_t)(p - (char*)d_ws);

    // Stage 1: GEMM (both paths need it)
    int gemm_blocks = (n_nodes + BM - 1) / BM;
    gcn_gemm_kernel<<<gemm_blocks, 256, 0, stream>>>(x, w, support, n_nodes);

    const int eb = (n_edges + 255) / 256;

    if (ws_size >= needed && scan_blocks <= 256) {
        // Stage 2: CSR build
        hipMemsetAsync(deg, 0, (size_t)n_nodes * sizeof(int), stream);
        gcn_hist_kernel<<<eb, 256, 0, stream>>>(rows, deg, n_edges);
        gcn_scan1_kernel<<<scan_blocks, 256, 0, stream>>>(deg, offsets, bsums, n_nodes);
        gcn_scan2_kernel<<<1, 256, 0, stream>>>(bsums, scan_blocks);
        gcn_scan3_kernel<<<scan_blocks, 256, 0, stream>>>(offsets, bsums, n_nodes);
        gcn_fill_kernel<<<eb, 256, 0, stream>>>(rows, cols, vals, offsets,
                                                csr_cv, n_edges);
        // Stage 3: atomic-free accumulate + fused ReLU
        int gb = (n_nodes + 3) / 4;
        gcn_gather_kernel<<<gb, 256, 0, stream>>>(support, offsets,
                                                  csr_cv, out, n_nodes);
    } else {
        // fallback: proven atomic path
        hipMemsetAsync(d_out, 0, (size_t)out_size * sizeof(float), stream);
        long long total = (long long)n_edges * (OUT_F / 4);
        int sc_blocks = (int)((total + 255) / 256);
        gcn_scatter_kernel<<<sc_blocks, 256, 0, stream>>>(support, vals, rows, cols,
                                                          out, n_edges);
        int n4 = out_size / 4;
        gcn_relu_kernel<<<(n4 + 255) / 256, 256, 0, stream>>>(out, n4);
    }
}

// Round 8
// 174.111 us; speedup vs baseline: 1.2156x; 1.2087x over previous
//
#include <hip/hip_runtime.h>
#include <hip/hip_bf16.h>

// ---------------------------------------------------------------------------
// GCN layer: out = relu(segment_sum(adj_vals * (x@W)[cols], rows))
//   x: [50000,256] f32, W: [256,128] f32, edges: 800000
// Stage 0: split W into bf16 hi/lo, transposed [col][k]  (tiny kernel)
// Stage 1: MFMA GEMM support = x @ W via split-bf16:
//            x = xh+xl, W = wh+wl;  acc += xh*wh + xl*wh + xh*wl
//          16x16x32 bf16 MFMA; 64x128 block tile, 4 waves, 32x64/wave.
// Stage 2: CSR build: hist -> 3-pass multiblock scan -> fill (int2 cv)
// Stage 3: per-node gather-accumulate + ReLU    (atomic-free, fused)
// Fallback (ws too small): VALU GEMM + atomicAdd scatter path.
// ---------------------------------------------------------------------------

#define IN_F  256
#define OUT_F 128

#define BM 64        // rows per block (MFMA path)
#define BK 32        // fp32 K per step
#define KP 40        // padded K dim in LDS (bf16 elems): 80B rows, 16B-aligned

typedef __attribute__((ext_vector_type(8))) short s16x8;
typedef __attribute__((ext_vector_type(4))) float f32x4;

static __device__ __forceinline__ unsigned short f2bf(float f) {
    union { float f; unsigned u; } v; v.f = f;
    unsigned r = v.u + 0x7FFFu + ((v.u >> 16) & 1u);   // RNE
    return (unsigned short)(r >> 16);
}
static __device__ __forceinline__ float bf2f(unsigned short b) {
    union { unsigned u; float f; } v; v.u = ((unsigned)b) << 16;
    return v.f;
}

// ------------------- Stage 0: W split (hi/lo bf16, transposed) -------------
// wh_T/wl_T layout: [OUT_F col][IN_F k] bf16
__global__ __launch_bounds__(256) void gcn_wsplit_kernel(
    const float* __restrict__ w, unsigned short* __restrict__ wh_T,
    unsigned short* __restrict__ wl_T)
{
    int cell = blockIdx.x * 256 + threadIdx.x;   // (c, kq): 128 x 64 = 8192
    int c  = cell & (OUT_F - 1);
    int kq = cell >> 7;                          // 0..63, 4 k each
    unsigned short h[4], l[4];
#pragma unroll
    for (int d = 0; d < 4; ++d) {
        float f = w[(size_t)(kq * 4 + d) * OUT_F + c];
        h[d] = f2bf(f);
        l[d] = f2bf(f - bf2f(h[d]));
    }
    *reinterpret_cast<ushort4*>(&wh_T[(size_t)c * IN_F + kq * 4]) =
        make_ushort4(h[0], h[1], h[2], h[3]);
    *reinterpret_cast<ushort4*>(&wl_T[(size_t)c * IN_F + kq * 4]) =
        make_ushort4(l[0], l[1], l[2], l[3]);
}

// ---------------------- Stage 1: MFMA GEMM (split-bf16) --------------------
__global__ __launch_bounds__(256) void gcn_gemm_mfma_kernel(
    const float* __restrict__ x,
    const unsigned short* __restrict__ wh_T,
    const unsigned short* __restrict__ wl_T,
    float* __restrict__ support, int n_nodes)
{
    __shared__ unsigned short xh_lds[BM][KP];      // 5 KB
    __shared__ unsigned short xl_lds[BM][KP];      // 5 KB
    __shared__ unsigned short wh_lds[OUT_F][KP];   // 10 KB
    __shared__ unsigned short wl_lds[OUT_F][KP];   // 10 KB

    const int tid  = threadIdx.x;
    const int lane = tid & 63;
    const int wid  = tid >> 6;            // 0..3
    const int wm   = (wid >> 1) * 32;     // wave row offset in tile
    const int wn   = (wid & 1) * 64;      // wave col offset
    const int row0 = blockIdx.x * BM;

    const int lr = lane & 15;             // fragment row/col index
    const int lg = lane >> 4;             // k-group 0..3

    f32x4 acc[2][4];
#pragma unroll
    for (int st = 0; st < 2; ++st)
#pragma unroll
        for (int nt = 0; nt < 4; ++nt)
            acc[st][nt] = (f32x4){0.f, 0.f, 0.f, 0.f};

    for (int k0 = 0; k0 < IN_F; k0 += BK) {
        if (k0 > 0) __syncthreads();

        // --- stage x tile: 64 rows x 32 k fp32 -> split bf16, LDS ---
        // cells (r, kq): 64 x 8 = 512 -> 2 iters
#pragma unroll
        for (int i = 0; i < 2; ++i) {
            int cell = i * 256 + tid;
            int r    = cell >> 3;
            int kq   = cell & 7;
            int row  = row0 + r;
            float4 xv = make_float4(0.f, 0.f, 0.f, 0.f);
            if (row < n_nodes)
                xv = *reinterpret_cast<const float4*>(
                    &x[(size_t)row * IN_F + k0 + kq * 4]);
            unsigned short h0 = f2bf(xv.x), h1 = f2bf(xv.y),
                           h2 = f2bf(xv.z), h3 = f2bf(xv.w);
            *reinterpret_cast<ushort4*>(&xh_lds[r][kq * 4]) =
                make_ushort4(h0, h1, h2, h3);
            *reinterpret_cast<ushort4*>(&xl_lds[r][kq * 4]) =
                make_ushort4(f2bf(xv.x - bf2f(h0)), f2bf(xv.y - bf2f(h1)),
                             f2bf(xv.z - bf2f(h2)), f2bf(xv.w - bf2f(h3)));
        }
        // --- stage W tile: 128 cols x 32 k bf16 (pre-split, [c][k]) ---
        // cells (c, p): 128 x 4 = 512 -> 2 iters, 16B each
#pragma unroll
        for (int i = 0; i < 2; ++i) {
            int cell = i * 256 + tid;
            int c    = cell >> 2;
            int p    = cell & 3;
            s16x8 hv = *reinterpret_cast<const s16x8*>(
                &wh_T[(size_t)c * IN_F + k0 + p * 8]);
            s16x8 lv = *reinterpret_cast<const s16x8*>(
                &wl_T[(size_t)c * IN_F + k0 + p * 8]);
            *reinterpret_cast<s16x8*>(&wh_lds[c][p * 8]) = hv;
            *reinterpret_cast<s16x8*>(&wl_lds[c][p * 8]) = lv;
        }
        __syncthreads();

        // --- fragment loads (K=32 covered per frag) ---
        s16x8 ah[2], al[2], bh[4], bl[4];
#pragma unroll
        for (int st = 0; st < 2; ++st) {
            int m = wm + st * 16 + lr;
            ah[st] = *reinterpret_cast<const s16x8*>(&xh_lds[m][lg * 8]);
            al[st] = *reinterpret_cast<const s16x8*>(&xl_lds[m][lg * 8]);
        }
#pragma unroll
        for (int nt = 0; nt < 4; ++nt) {
            int c = wn + nt * 16 + lr;
            bh[nt] = *reinterpret_cast<const s16x8*>(&wh_lds[c][lg * 8]);
            bl[nt] = *reinterpret_cast<const s16x8*>(&wl_lds[c][lg * 8]);
        }

        // --- 24 MFMAs: acc += xh*wh + xl*wh + xh*wl ---
#pragma unroll
        for (int st = 0; st < 2; ++st)
#pragma unroll
            for (int nt = 0; nt < 4; ++nt) {
                acc[st][nt] = __builtin_amdgcn_mfma_f32_16x16x32_bf16(
                    ah[st], bh[nt], acc[st][nt], 0, 0, 0);
                acc[st][nt] = __builtin_amdgcn_mfma_f32_16x16x32_bf16(
                    al[st], bh[nt], acc[st][nt], 0, 0, 0);
                acc[st][nt] = __builtin_amdgcn_mfma_f32_16x16x32_bf16(
                    ah[st], bl[nt], acc[st][nt], 0, 0, 0);
            }
    }

    // --- epilogue: C/D layout col=lane&15, row=(lane>>4)*4+reg (m89) ---
#pragma unroll
    for (int st = 0; st < 2; ++st) {
#pragma unroll
        for (int nt = 0; nt < 4; ++nt) {
#pragma unroll
            for (int r = 0; r < 4; ++r) {
                int m = row0 + wm + st * 16 + lg * 4 + r;
                int n = wn + nt * 16 + lr;
                if (m < n_nodes)
                    support[(size_t)m * OUT_F + n] = acc[st][nt][r];
            }
        }
    }
}

// ------------------- Fallback Stage 1: VALU GEMM (proven R5) ---------------
#define VBK 32
#define XPAD 68
__global__ __launch_bounds__(256) void gcn_gemm_valu_kernel(
    const float* __restrict__ x, const float* __restrict__ w,
    float* __restrict__ support, int n_nodes)
{
    __shared__ float xs_t[VBK][XPAD];
    __shared__ float ws_[VBK][OUT_F];

    const int tid  = threadIdx.x;
    const int cg   = tid & 31;
    const int rg   = tid >> 5;
    const int row0 = blockIdx.x * BM;

    float acc[8][4];
#pragma unroll
    for (int i = 0; i < 8; ++i)
#pragma unroll
        for (int j = 0; j < 4; ++j) acc[i][j] = 0.f;

    for (int k0 = 0; k0 < IN_F; k0 += VBK) {
        if (k0 > 0) __syncthreads();
#pragma unroll
        for (int i = 0; i < 2; ++i) {
            int t   = tid + i * 256;
            int r   = t >> 3;
            int kk  = (t & 7) << 2;
            int row = row0 + r;
            float4 v = make_float4(0.f, 0.f, 0.f, 0.f);
            if (row < n_nodes)
                v = *reinterpret_cast<const float4*>(&x[(size_t)row * IN_F + k0 + kk]);
            xs_t[kk + 0][r] = v.x;
            xs_t[kk + 1][r] = v.y;
            xs_t[kk + 2][r] = v.z;
            xs_t[kk + 3][r] = v.w;
        }
#pragma unroll
        for (int i = 0; i < 4; ++i) {
            int fi = tid + i * 256;
            int kk = fi >> 5;
            int cc = (fi & 31) << 2;
            *reinterpret_cast<float4*>(&ws_[kk][cc]) =
                *reinterpret_cast<const float4*>(&w[(size_t)(k0 + kk) * OUT_F + cc]);
        }
        __syncthreads();
#pragma unroll
        for (int kk = 0; kk < VBK; ++kk) {
            float4 a0 = *reinterpret_cast<const float4*>(&xs_t[kk][rg * 4]);
            float4 a1 = *reinterpret_cast<const float4*>(&xs_t[kk][rg * 4 + 32]);
            float4 b  = *reinterpret_cast<const float4*>(&ws_[kk][cg * 4]);
            const float av[8] = {a0.x, a0.y, a0.z, a0.w, a1.x, a1.y, a1.z, a1.w};
            const float bv[4] = {b.x, b.y, b.z, b.w};
#pragma unroll
            for (int i = 0; i < 8; ++i)
#pragma unroll
                for (int j = 0; j < 4; ++j)
                    acc[i][j] += av[i] * bv[j];
        }
    }
#pragma unroll
    for (int i = 0; i < 8; ++i) {
        int row = row0 + rg * 4 + (i & 3) + (i >> 2) * 32;
        if (row < n_nodes) {
            float4 o = make_float4(acc[i][0], acc[i][1], acc[i][2], acc[i][3]);
            *reinterpret_cast<float4*>(&support[(size_t)row * OUT_F + cg * 4]) = o;
        }
    }
}

// ------------------------- Stage 2: CSR build ------------------------------
__global__ __launch_bounds__(256) void gcn_hist_kernel(
    const int* __restrict__ rows, int* __restrict__ deg, int n_edges)
{
    int e = blockIdx.x * blockDim.x + threadIdx.x;
    if (e < n_edges) atomicAdd(&deg[rows[e]], 1);
}

__global__ __launch_bounds__(256) void gcn_scan1_kernel(
    const int* __restrict__ deg, int* __restrict__ offsets,
    int* __restrict__ block_sums, int n)
{
    __shared__ int part[256];
    const int tid  = threadIdx.x;
    const int base = blockIdx.x * 1024 + tid * 4;

    int4 v = make_int4(0, 0, 0, 0);
    if (base + 3 < n) {
        v = *reinterpret_cast<const int4*>(&deg[base]);
    } else {
        if (base + 0 < n) v.x = deg[base + 0];
        if (base + 1 < n) v.y = deg[base + 1];
        if (base + 2 < n) v.z = deg[base + 2];
        if (base + 3 < n) v.w = deg[base + 3];
    }
    int s = v.x + v.y + v.z + v.w;
    part[tid] = s;
    __syncthreads();
    for (int d = 1; d < 256; d <<= 1) {
        int t = (tid >= d) ? part[tid - d] : 0;
        __syncthreads();
        part[tid] += t;
        __syncthreads();
    }
    int ex = part[tid] - s;
    int4 o;
    o.x = ex;
    o.y = o.x + v.x;
    o.z = o.y + v.y;
    o.w = o.z + v.z;
    if (base + 3 < n) {
        *reinterpret_cast<int4*>(&offsets[base]) = o;
    } else {
        if (base + 0 < n) offsets[base + 0] = o.x;
        if (base + 1 < n) offsets[base + 1] = o.y;
        if (base + 2 < n) offsets[base + 2] = o.z;
        if (base + 3 < n) offsets[base + 3] = o.w;
    }
    if (tid == 255) block_sums[blockIdx.x] = part[255];
}

__global__ __launch_bounds__(256) void gcn_scan2_kernel(
    int* __restrict__ block_sums, int nb)
{
    __shared__ int part[256];
    const int tid = threadIdx.x;
    int s = (tid < nb) ? block_sums[tid] : 0;
    part[tid] = s;
    __syncthreads();
    for (int d = 1; d < 256; d <<= 1) {
        int t = (tid >= d) ? part[tid - d] : 0;
        __syncthreads();
        part[tid] += t;
        __syncthreads();
    }
    if (tid < nb) block_sums[tid] = part[tid] - s;
}

__global__ __launch_bounds__(256) void gcn_scan3_kernel(
    int* __restrict__ offsets, const int* __restrict__ block_sums, int n)
{
    const int base = blockIdx.x * 1024 + threadIdx.x * 4;
    const int add  = block_sums[blockIdx.x];
    if (base + 3 < n) {
        int4 v = *reinterpret_cast<const int4*>(&offsets[base]);
        v.x += add; v.y += add; v.z += add; v.w += add;
        *reinterpret_cast<int4*>(&offsets[base]) = v;
    } else {
        if (base + 0 < n) offsets[base + 0] += add;
        if (base + 1 < n) offsets[base + 1] += add;
        if (base + 2 < n) offsets[base + 2] += add;
        if (base + 3 < n) offsets[base + 3] += add;
    }
}

__global__ __launch_bounds__(256) void gcn_fill_kernel(
    const int* __restrict__ rows, const int* __restrict__ cols,
    const float* __restrict__ vals, int* __restrict__ offsets,
    int2* __restrict__ csr_cv, int n_edges)
{
    int e = blockIdx.x * blockDim.x + threadIdx.x;
    if (e >= n_edges) return;
    int r = rows[e];
    int pos = atomicAdd(&offsets[r], 1);
    int2 cv;
    cv.x = cols[e];
    cv.y = __float_as_int(vals[e]);
    csr_cv[pos] = cv;
}

// ---------------- Stage 3: per-node accumulate + ReLU ----------------------
__global__ __launch_bounds__(256) void gcn_gather_kernel(
    const float* __restrict__ support, const int* __restrict__ offsets,
    const int2* __restrict__ csr_cv, float* __restrict__ out, int n_nodes)
{
    const int node = blockIdx.x * 4 + (threadIdx.x >> 6);
    const int lane = threadIdx.x & 63;
    if (node >= n_nodes) return;

    const int end   = offsets[node];
    const int start = (node == 0) ? 0 : offsets[node - 1];
    const int d     = end - start;
    const int off   = start;

    float2 acc = make_float2(0.f, 0.f);
    int j = 0;
    for (; j + 3 < d; j += 4) {
        int2 cv0 = csr_cv[off + j];
        int2 cv1 = csr_cv[off + j + 1];
        int2 cv2 = csr_cv[off + j + 2];
        int2 cv3 = csr_cv[off + j + 3];
        float v0 = __int_as_float(cv0.y);
        float v1 = __int_as_float(cv1.y);
        float v2 = __int_as_float(cv2.y);
        float v3 = __int_as_float(cv3.y);
        float2 s0 = *reinterpret_cast<const float2*>(&support[(size_t)cv0.x * OUT_F + lane * 2]);
        float2 s1 = *reinterpret_cast<const float2*>(&support[(size_t)cv1.x * OUT_F + lane * 2]);
        float2 s2 = *reinterpret_cast<const float2*>(&support[(size_t)cv2.x * OUT_F + lane * 2]);
        float2 s3 = *reinterpret_cast<const float2*>(&support[(size_t)cv3.x * OUT_F + lane * 2]);
        acc.x += v0 * s0.x + v1 * s1.x + v2 * s2.x + v3 * s3.x;
        acc.y += v0 * s0.y + v1 * s1.y + v2 * s2.y + v3 * s3.y;
    }
    for (; j < d; ++j) {
        int2 cv0 = csr_cv[off + j];
        float v0 = __int_as_float(cv0.y);
        float2 s0 = *reinterpret_cast<const float2*>(&support[(size_t)cv0.x * OUT_F + lane * 2]);
        acc.x += v0 * s0.x;
        acc.y += v0 * s0.y;
    }

    float2 o;
    o.x = fmaxf(acc.x, 0.f);
    o.y = fmaxf(acc.y, 0.f);
    *reinterpret_cast<float2*>(&out[(size_t)node * OUT_F + lane * 2]) = o;
}

// ------------------------- Fallback (atomic) -------------------------------
__global__ __launch_bounds__(256) void gcn_scatter_kernel(
    const float* __restrict__ support, const float* __restrict__ vals,
    const int* __restrict__ rows, const int* __restrict__ cols,
    float* __restrict__ out, int n_edges)
{
    long long idx   = (long long)blockIdx.x * blockDim.x + threadIdx.x;
    long long total = (long long)n_edges * (OUT_F / 4);
    if (idx >= total) return;

    int e  = (int)(idx >> 5);
    int f4 = (int)(idx & 31);
    int r  = rows[e];
    int c  = cols[e];
    float v = vals[e];

    float4 s = *reinterpret_cast<const float4*>(&support[(size_t)c * OUT_F + f4 * 4]);
    float* o = &out[(size_t)r * OUT_F + f4 * 4];
    atomicAdd(o + 0, v * s.x);
    atomicAdd(o + 1, v * s.y);
    atomicAdd(o + 2, v * s.z);
    atomicAdd(o + 3, v * s.w);
}

__global__ __launch_bounds__(256) void gcn_relu_kernel(float* __restrict__ out, int n4)
{
    int idx = blockIdx.x * blockDim.x + threadIdx.x;
    if (idx >= n4) return;
    float4* p = reinterpret_cast<float4*>(out) + idx;
    float4 v = *p;
    v.x = fmaxf(v.x, 0.f);
    v.y = fmaxf(v.y, 0.f);
    v.z = fmaxf(v.z, 0.f);
    v.w = fmaxf(v.w, 0.f);
    *p = v;
}

// ---------------------------------------------------------------------------
static inline char* align16(char* p) {
    return (char*)(((uintptr_t)p + 15) & ~(uintptr_t)15);
}

extern "C" void kernel_launch(void* const* d_in, const int* in_sizes, int n_in,
                              void* d_out, int out_size, void* d_ws, size_t ws_size,
                              hipStream_t stream)
{
    const float* x    = (const float*)d_in[0];
    const float* w    = (const float*)d_in[1];
    const float* vals = (const float*)d_in[2];
    const int*   rows = (const int*)d_in[3];
    const int*   cols = (const int*)d_in[4];
    float* out = (float*)d_out;

    const int n_nodes = in_sizes[0] / IN_F;     // 50000
    const int n_edges = in_sizes[2];            // 800000

    const int scan_blocks = (n_nodes + 1023) / 1024;

    // workspace layout (16B-aligned slots)
    char* p = (char*)d_ws;
    float*          support = (float*)p;          p = align16(p + (size_t)n_nodes * OUT_F * sizeof(float));
    unsigned short* wh_T    = (unsigned short*)p; p = align16(p + (size_t)OUT_F * IN_F * sizeof(short));
    unsigned short* wl_T    = (unsigned short*)p; p = align16(p + (size_t)OUT_F * IN_F * sizeof(short));
    int*            offsets = (int*)p;            p = align16(p + (size_t)n_nodes * sizeof(int));
    int*            deg     = (int*)p;            p = align16(p + (size_t)n_nodes * sizeof(int));
    int*            bsums   = (int*)p;            p = align16(p + (size_t)256 * sizeof(int));
    int2*           csr_cv  = (int2*)p;           p = align16(p + (size_t)n_edges * sizeof(int2));
    size_t needed = (size_t)(p - (char*)d_ws);

    const int gemm_blocks = (n_nodes + BM - 1) / BM;
    const int eb = (n_edges + 255) / 256;

    if (ws_size >= needed && scan_blocks <= 256) {
        // Stage 0 + 1: W split, then MFMA GEMM
        gcn_wsplit_kernel<<<(OUT_F * IN_F / 4) / 256, 256, 0, stream>>>(w, wh_T, wl_T);
        gcn_gemm_mfma_kernel<<<gemm_blocks, 256, 0, stream>>>(x, wh_T, wl_T,
                                                              support, n_nodes);
        // Stage 2: CSR build
        hipMemsetAsync(deg, 0, (size_t)n_nodes * sizeof(int), stream);
        gcn_hist_kernel<<<eb, 256, 0, stream>>>(rows, deg, n_edges);
        gcn_scan1_kernel<<<scan_blocks, 256, 0, stream>>>(deg, offsets, bsums, n_nodes);
        gcn_scan2_kernel<<<1, 256, 0, stream>>>(bsums, scan_blocks);
        gcn_scan3_kernel<<<scan_blocks, 256, 0, stream>>>(offsets, bsums, n_nodes);
        gcn_fill_kernel<<<eb, 256, 0, stream>>>(rows, cols, vals, offsets,
                                                csr_cv, n_edges);
        // Stage 3: atomic-free accumulate + fused ReLU
        int gb = (n_nodes + 3) / 4;
        gcn_gather_kernel<<<gb, 256, 0, stream>>>(support, offsets,
                                                  csr_cv, out, n_nodes);
    } else {
        // fallback: VALU GEMM + atomic scatter (needs only support in ws)
        gcn_gemm_valu_kernel<<<gemm_blocks, 256, 0, stream>>>(x, w, support, n_nodes);
        hipMemsetAsync(d_out, 0, (size_t)out_size * sizeof(float), stream);
        long long total = (long long)n_edges * (OUT_F / 4);
        int sc_blocks = (int)((total + 255) / 256);
        gcn_scatter_kernel<<<sc_blocks, 256, 0, stream>>>(support, vals, rows, cols,
                                                          out, n_edges);
        int n4 = out_size / 4;
        gcn_relu_kernel<<<(n4 + 255) / 256, 256, 0, stream>>>(out, n4);
    }
}

// Round 9
// 160.496 us; speedup vs baseline: 1.3187x; 1.0848x over previous
//
#include <hip/hip_runtime.h>
#include <hip/hip_bf16.h>

// ---------------------------------------------------------------------------
// GCN layer: out = relu(segment_sum(adj_vals * (x@W)[cols], rows))
//   x: [50000,256] f32, W: [256,128] f32, edges: 800000
// Stage 0: split W into bf16 hi/lo, transposed [col][k]  (tiny kernel)
// Stage 1: MFMA GEMM support = x @ W via split-bf16 (3 terms), output
//          rounded to bf16 (halves all downstream gather bytes).
// Stage 2: CSR build: hist -> 3-pass multiblock scan -> fill into PACKED
//          4B entries (bf16 val << 16 | col), nontemporal stores.
// Stage 3: per-node gather-accumulate (bf16 support rows) + ReLU, f32 out.
// Fallback (ws too small or n_nodes >= 65536): VALU GEMM + atomic scatter.
// ---------------------------------------------------------------------------

#define IN_F  256
#define OUT_F 128

#define BM 64        // rows per block (MFMA path)
#define BK 32        // fp32 K per step
#define KP 40        // padded K dim in LDS (bf16 elems): 80B rows, 16B-aligned

typedef __attribute__((ext_vector_type(8))) short s16x8;
typedef __attribute__((ext_vector_type(4))) float f32x4;

static __device__ __forceinline__ unsigned short f2bf(float f) {
    union { float f; unsigned u; } v; v.f = f;
    unsigned r = v.u + 0x7FFFu + ((v.u >> 16) & 1u);   // RNE
    return (unsigned short)(r >> 16);
}
static __device__ __forceinline__ float bf2f(unsigned short b) {
    union { unsigned u; float f; } v; v.u = ((unsigned)b) << 16;
    return v.f;
}

// ------------------- Stage 0: W split (hi/lo bf16, transposed) -------------
__global__ __launch_bounds__(256) void gcn_wsplit_kernel(
    const float* __restrict__ w, unsigned short* __restrict__ wh_T,
    unsigned short* __restrict__ wl_T)
{
    int cell = blockIdx.x * 256 + threadIdx.x;   // (c, kq): 128 x 64 = 8192
    int c  = cell & (OUT_F - 1);
    int kq = cell >> 7;                          // 0..63, 4 k each
    unsigned short h[4], l[4];
#pragma unroll
    for (int d = 0; d < 4; ++d) {
        float f = w[(size_t)(kq * 4 + d) * OUT_F + c];
        h[d] = f2bf(f);
        l[d] = f2bf(f - bf2f(h[d]));
    }
    *reinterpret_cast<ushort4*>(&wh_T[(size_t)c * IN_F + kq * 4]) =
        make_ushort4(h[0], h[1], h[2], h[3]);
    *reinterpret_cast<ushort4*>(&wl_T[(size_t)c * IN_F + kq * 4]) =
        make_ushort4(l[0], l[1], l[2], l[3]);
}

// ---------------------- Stage 1: MFMA GEMM (split-bf16) --------------------
// output: support_bf [n_nodes][OUT_F] bf16
__global__ __launch_bounds__(256) void gcn_gemm_mfma_kernel(
    const float* __restrict__ x,
    const unsigned short* __restrict__ wh_T,
    const unsigned short* __restrict__ wl_T,
    unsigned short* __restrict__ support_bf, int n_nodes)
{
    __shared__ unsigned short xh_lds[BM][KP];      // 5 KB
    __shared__ unsigned short xl_lds[BM][KP];      // 5 KB
    __shared__ unsigned short wh_lds[OUT_F][KP];   // 10 KB
    __shared__ unsigned short wl_lds[OUT_F][KP];   // 10 KB

    const int tid  = threadIdx.x;
    const int lane = tid & 63;
    const int wid  = tid >> 6;            // 0..3
    const int wm   = (wid >> 1) * 32;     // wave row offset in tile
    const int wn   = (wid & 1) * 64;      // wave col offset
    const int row0 = blockIdx.x * BM;

    const int lr = lane & 15;             // fragment row/col index
    const int lg = lane >> 4;             // k-group 0..3

    f32x4 acc[2][4];
#pragma unroll
    for (int st = 0; st < 2; ++st)
#pragma unroll
        for (int nt = 0; nt < 4; ++nt)
            acc[st][nt] = (f32x4){0.f, 0.f, 0.f, 0.f};

    for (int k0 = 0; k0 < IN_F; k0 += BK) {
        if (k0 > 0) __syncthreads();

        // --- stage x tile: 64 rows x 32 k fp32 -> split bf16, LDS ---
#pragma unroll
        for (int i = 0; i < 2; ++i) {
            int cell = i * 256 + tid;
            int r    = cell >> 3;
            int kq   = cell & 7;
            int row  = row0 + r;
            float4 xv = make_float4(0.f, 0.f, 0.f, 0.f);
            if (row < n_nodes)
                xv = *reinterpret_cast<const float4*>(
                    &x[(size_t)row * IN_F + k0 + kq * 4]);
            unsigned short h0 = f2bf(xv.x), h1 = f2bf(xv.y),
                           h2 = f2bf(xv.z), h3 = f2bf(xv.w);
            *reinterpret_cast<ushort4*>(&xh_lds[r][kq * 4]) =
                make_ushort4(h0, h1, h2, h3);
            *reinterpret_cast<ushort4*>(&xl_lds[r][kq * 4]) =
                make_ushort4(f2bf(xv.x - bf2f(h0)), f2bf(xv.y - bf2f(h1)),
                             f2bf(xv.z - bf2f(h2)), f2bf(xv.w - bf2f(h3)));
        }
        // --- stage W tile: 128 cols x 32 k bf16 (pre-split, [c][k]) ---
#pragma unroll
        for (int i = 0; i < 2; ++i) {
            int cell = i * 256 + tid;
            int c    = cell >> 2;
            int p    = cell & 3;
            s16x8 hv = *reinterpret_cast<const s16x8*>(
                &wh_T[(size_t)c * IN_F + k0 + p * 8]);
            s16x8 lv = *reinterpret_cast<const s16x8*>(
                &wl_T[(size_t)c * IN_F + k0 + p * 8]);
            *reinterpret_cast<s16x8*>(&wh_lds[c][p * 8]) = hv;
            *reinterpret_cast<s16x8*>(&wl_lds[c][p * 8]) = lv;
        }
        __syncthreads();

        // --- fragment loads (K=32 covered per frag) ---
        s16x8 ah[2], al[2], bh[4], bl[4];
#pragma unroll
        for (int st = 0; st < 2; ++st) {
            int m = wm + st * 16 + lr;
            ah[st] = *reinterpret_cast<const s16x8*>(&xh_lds[m][lg * 8]);
            al[st] = *reinterpret_cast<const s16x8*>(&xl_lds[m][lg * 8]);
        }
#pragma unroll
        for (int nt = 0; nt < 4; ++nt) {
            int c = wn + nt * 16 + lr;
            bh[nt] = *reinterpret_cast<const s16x8*>(&wh_lds[c][lg * 8]);
            bl[nt] = *reinterpret_cast<const s16x8*>(&wl_lds[c][lg * 8]);
        }

        // --- 24 MFMAs: acc += xh*wh + xl*wh + xh*wl ---
#pragma unroll
        for (int st = 0; st < 2; ++st)
#pragma unroll
            for (int nt = 0; nt < 4; ++nt) {
                acc[st][nt] = __builtin_amdgcn_mfma_f32_16x16x32_bf16(
                    ah[st], bh[nt], acc[st][nt], 0, 0, 0);
                acc[st][nt] = __builtin_amdgcn_mfma_f32_16x16x32_bf16(
                    al[st], bh[nt], acc[st][nt], 0, 0, 0);
                acc[st][nt] = __builtin_amdgcn_mfma_f32_16x16x32_bf16(
                    ah[st], bl[nt], acc[st][nt], 0, 0, 0);
            }
    }

    // --- epilogue: C/D layout col=lane&15, row=(lane>>4)*4+reg (m89) ---
#pragma unroll
    for (int st = 0; st < 2; ++st) {
#pragma unroll
        for (int nt = 0; nt < 4; ++nt) {
#pragma unroll
            for (int r = 0; r < 4; ++r) {
                int m = row0 + wm + st * 16 + lg * 4 + r;
                int n = wn + nt * 16 + lr;
                if (m < n_nodes)
                    support_bf[(size_t)m * OUT_F + n] = f2bf(acc[st][nt][r]);
            }
        }
    }
}

// ------------------- Fallback Stage 1: VALU GEMM (proven R5) ---------------
#define VBK 32
#define XPAD 68
__global__ __launch_bounds__(256) void gcn_gemm_valu_kernel(
    const float* __restrict__ x, const float* __restrict__ w,
    float* __restrict__ support, int n_nodes)
{
    __shared__ float xs_t[VBK][XPAD];
    __shared__ float ws_[VBK][OUT_F];

    const int tid  = threadIdx.x;
    const int cg   = tid & 31;
    const int rg   = tid >> 5;
    const int row0 = blockIdx.x * BM;

    float acc[8][4];
#pragma unroll
    for (int i = 0; i < 8; ++i)
#pragma unroll
        for (int j = 0; j < 4; ++j) acc[i][j] = 0.f;

    for (int k0 = 0; k0 < IN_F; k0 += VBK) {
        if (k0 > 0) __syncthreads();
#pragma unroll
        for (int i = 0; i < 2; ++i) {
            int t   = tid + i * 256;
            int r   = t >> 3;
            int kk  = (t & 7) << 2;
            int row = row0 + r;
            float4 v = make_float4(0.f, 0.f, 0.f, 0.f);
            if (row < n_nodes)
                v = *reinterpret_cast<const float4*>(&x[(size_t)row * IN_F + k0 + kk]);
            xs_t[kk + 0][r] = v.x;
            xs_t[kk + 1][r] = v.y;
            xs_t[kk + 2][r] = v.z;
            xs_t[kk + 3][r] = v.w;
        }
#pragma unroll
        for (int i = 0; i < 4; ++i) {
            int fi = tid + i * 256;
            int kk = fi >> 5;
            int cc = (fi & 31) << 2;
            *reinterpret_cast<float4*>(&ws_[kk][cc]) =
                *reinterpret_cast<const float4*>(&w[(size_t)(k0 + kk) * OUT_F + cc]);
        }
        __syncthreads();
#pragma unroll
        for (int kk = 0; kk < VBK; ++kk) {
            float4 a0 = *reinterpret_cast<const float4*>(&xs_t[kk][rg * 4]);
            float4 a1 = *reinterpret_cast<const float4*>(&xs_t[kk][rg * 4 + 32]);
            float4 b  = *reinterpret_cast<const float4*>(&ws_[kk][cg * 4]);
            const float av[8] = {a0.x, a0.y, a0.z, a0.w, a1.x, a1.y, a1.z, a1.w};
            const float bv[4] = {b.x, b.y, b.z, b.w};
#pragma unroll
            for (int i = 0; i < 8; ++i)
#pragma unroll
                for (int j = 0; j < 4; ++j)
                    acc[i][j] += av[i] * bv[j];
        }
    }
#pragma unroll
    for (int i = 0; i < 8; ++i) {
        int row = row0 + rg * 4 + (i & 3) + (i >> 2) * 32;
        if (row < n_nodes) {
            float4 o = make_float4(acc[i][0], acc[i][1], acc[i][2], acc[i][3]);
            *reinterpret_cast<float4*>(&support[(size_t)row * OUT_F + cg * 4]) = o;
        }
    }
}

// ------------------------- Stage 2: CSR build ------------------------------
__global__ __launch_bounds__(256) void gcn_hist_kernel(
    const int* __restrict__ rows, int* __restrict__ deg, int n_edges)
{
    int e = blockIdx.x * blockDim.x + threadIdx.x;
    if (e < n_edges) atomicAdd(&deg[rows[e]], 1);
}

__global__ __launch_bounds__(256) void gcn_scan1_kernel(
    const int* __restrict__ deg, int* __restrict__ offsets,
    int* __restrict__ block_sums, int n)
{
    __shared__ int part[256];
    const int tid  = threadIdx.x;
    const int base = blockIdx.x * 1024 + tid * 4;

    int4 v = make_int4(0, 0, 0, 0);
    if (base + 3 < n) {
        v = *reinterpret_cast<const int4*>(&deg[base]);
    } else {
        if (base + 0 < n) v.x = deg[base + 0];
        if (base + 1 < n) v.y = deg[base + 1];
        if (base + 2 < n) v.z = deg[base + 2];
        if (base + 3 < n) v.w = deg[base + 3];
    }
    int s = v.x + v.y + v.z + v.w;
    part[tid] = s;
    __syncthreads();
    for (int d = 1; d < 256; d <<= 1) {
        int t = (tid >= d) ? part[tid - d] : 0;
        __syncthreads();
        part[tid] += t;
        __syncthreads();
    }
    int ex = part[tid] - s;
    int4 o;
    o.x = ex;
    o.y = o.x + v.x;
    o.z = o.y + v.y;
    o.w = o.z + v.z;
    if (base + 3 < n) {
        *reinterpret_cast<int4*>(&offsets[base]) = o;
    } else {
        if (base + 0 < n) offsets[base + 0] = o.x;
        if (base + 1 < n) offsets[base + 1] = o.y;
        if (base + 2 < n) offsets[base + 2] = o.z;
        if (base + 3 < n) offsets[base + 3] = o.w;
    }
    if (tid == 255) block_sums[blockIdx.x] = part[255];
}

__global__ __launch_bounds__(256) void gcn_scan2_kernel(
    int* __restrict__ block_sums, int nb)
{
    __shared__ int part[256];
    const int tid = threadIdx.x;
    int s = (tid < nb) ? block_sums[tid] : 0;
    part[tid] = s;
    __syncthreads();
    for (int d = 1; d < 256; d <<= 1) {
        int t = (tid >= d) ? part[tid - d] : 0;
        __syncthreads();
        part[tid] += t;
        __syncthreads();
    }
    if (tid < nb) block_sums[tid] = part[tid] - s;
}

__global__ __launch_bounds__(256) void gcn_scan3_kernel(
    int* __restrict__ offsets, const int* __restrict__ block_sums, int n)
{
    const int base = blockIdx.x * 1024 + threadIdx.x * 4;
    const int add  = block_sums[blockIdx.x];
    if (base + 3 < n) {
        int4 v = *reinterpret_cast<const int4*>(&offsets[base]);
        v.x += add; v.y += add; v.z += add; v.w += add;
        *reinterpret_cast<int4*>(&offsets[base]) = v;
    } else {
        if (base + 0 < n) offsets[base + 0] += add;
        if (base + 1 < n) offsets[base + 1] += add;
        if (base + 2 < n) offsets[base + 2] += add;
        if (base + 3 < n) offsets[base + 3] += add;
    }
}

// --- fill: one packed 4B (val_bf16<<16 | col) nontemporal store per edge ---
__global__ __launch_bounds__(256) void gcn_fill_kernel(
    const int* __restrict__ rows, const int* __restrict__ cols,
    const float* __restrict__ vals, int* __restrict__ offsets,
    unsigned int* __restrict__ csr_cv, int n_edges)
{
    int e = blockIdx.x * blockDim.x + threadIdx.x;
    if (e >= n_edges) return;
    int r = rows[e];
    int pos = atomicAdd(&offsets[r], 1);
    unsigned int cv = ((unsigned int)f2bf(vals[e]) << 16) | (unsigned int)cols[e];
    __builtin_nontemporal_store(cv, &csr_cv[pos]);
}

// ---------------- Stage 3: per-node accumulate + ReLU ----------------------
// after fill, offsets[r] is the END pointer of row r; start = offsets[r-1]
__global__ __launch_bounds__(256) void gcn_gather_kernel(
    const unsigned short* __restrict__ support_bf,
    const int* __restrict__ offsets,
    const unsigned int* __restrict__ csr_cv,
    float* __restrict__ out, int n_nodes)
{
    const int node = blockIdx.x * 4 + (threadIdx.x >> 6);
    const int lane = threadIdx.x & 63;
    if (node >= n_nodes) return;

    const int end   = offsets[node];
    const int start = (node == 0) ? 0 : offsets[node - 1];
    const int d     = end - start;
    const int off   = start;

    float2 acc = make_float2(0.f, 0.f);
    int j = 0;
    for (; j + 3 < d; j += 4) {
        unsigned int cv0 = csr_cv[off + j];
        unsigned int cv1 = csr_cv[off + j + 1];
        unsigned int cv2 = csr_cv[off + j + 2];
        unsigned int cv3 = csr_cv[off + j + 3];
        ushort2 s0 = *reinterpret_cast<const ushort2*>(
            &support_bf[(size_t)(cv0 & 0xFFFFu) * OUT_F + lane * 2]);
        ushort2 s1 = *reinterpret_cast<const ushort2*>(
            &support_bf[(size_t)(cv1 & 0xFFFFu) * OUT_F + lane * 2]);
        ushort2 s2 = *reinterpret_cast<const ushort2*>(
            &support_bf[(size_t)(cv2 & 0xFFFFu) * OUT_F + lane * 2]);
        ushort2 s3 = *reinterpret_cast<const ushort2*>(
            &support_bf[(size_t)(cv3 & 0xFFFFu) * OUT_F + lane * 2]);
        float v0 = bf2f((unsigned short)(cv0 >> 16));
        float v1 = bf2f((unsigned short)(cv1 >> 16));
        float v2 = bf2f((unsigned short)(cv2 >> 16));
        float v3 = bf2f((unsigned short)(cv3 >> 16));
        acc.x += v0 * bf2f(s0.x) + v1 * bf2f(s1.x) + v2 * bf2f(s2.x) + v3 * bf2f(s3.x);
        acc.y += v0 * bf2f(s0.y) + v1 * bf2f(s1.y) + v2 * bf2f(s2.y) + v3 * bf2f(s3.y);
    }
    for (; j < d; ++j) {
        unsigned int cv0 = csr_cv[off + j];
        ushort2 s0 = *reinterpret_cast<const ushort2*>(
            &support_bf[(size_t)(cv0 & 0xFFFFu) * OUT_F + lane * 2]);
        float v0 = bf2f((unsigned short)(cv0 >> 16));
        acc.x += v0 * bf2f(s0.x);
        acc.y += v0 * bf2f(s0.y);
    }

    float2 o;
    o.x = fmaxf(acc.x, 0.f);
    o.y = fmaxf(acc.y, 0.f);
    *reinterpret_cast<float2*>(&out[(size_t)node * OUT_F + lane * 2]) = o;
}

// ------------------------- Fallback (atomic, f32 support) ------------------
__global__ __launch_bounds__(256) void gcn_scatter_kernel(
    const float* __restrict__ support, const float* __restrict__ vals,
    const int* __restrict__ rows, const int* __restrict__ cols,
    float* __restrict__ out, int n_edges)
{
    long long idx   = (long long)blockIdx.x * blockDim.x + threadIdx.x;
    long long total = (long long)n_edges * (OUT_F / 4);
    if (idx >= total) return;

    int e  = (int)(idx >> 5);
    int f4 = (int)(idx & 31);
    int r  = rows[e];
    int c  = cols[e];
    float v = vals[e];

    float4 s = *reinterpret_cast<const float4*>(&support[(size_t)c * OUT_F + f4 * 4]);
    float* o = &out[(size_t)r * OUT_F + f4 * 4];
    atomicAdd(o + 0, v * s.x);
    atomicAdd(o + 1, v * s.y);
    atomicAdd(o + 2, v * s.z);
    atomicAdd(o + 3, v * s.w);
}

__global__ __launch_bounds__(256) void gcn_relu_kernel(float* __restrict__ out, int n4)
{
    int idx = blockIdx.x * blockDim.x + threadIdx.x;
    if (idx >= n4) return;
    float4* p = reinterpret_cast<float4*>(out) + idx;
    float4 v = *p;
    v.x = fmaxf(v.x, 0.f);
    v.y = fmaxf(v.y, 0.f);
    v.z = fmaxf(v.z, 0.f);
    v.w = fmaxf(v.w, 0.f);
    *p = v;
}

// ---------------------------------------------------------------------------
static inline char* align16(char* p) {
    return (char*)(((uintptr_t)p + 15) & ~(uintptr_t)15);
}

extern "C" void kernel_launch(void* const* d_in, const int* in_sizes, int n_in,
                              void* d_out, int out_size, void* d_ws, size_t ws_size,
                              hipStream_t stream)
{
    const float* x    = (const float*)d_in[0];
    const float* w    = (const float*)d_in[1];
    const float* vals = (const float*)d_in[2];
    const int*   rows = (const int*)d_in[3];
    const int*   cols = (const int*)d_in[4];
    float* out = (float*)d_out;

    const int n_nodes = in_sizes[0] / IN_F;     // 50000
    const int n_edges = in_sizes[2];            // 800000

    const int scan_blocks = (n_nodes + 1023) / 1024;

    // workspace layout (16B-aligned slots).
    // support region sized for f32 (fallback); MFMA path uses it as bf16.
    char* p = (char*)d_ws;
    char*           supp_raw = p;                 p = align16(p + (size_t)n_nodes * OUT_F * sizeof(float));
    unsigned short* wh_T    = (unsigned short*)p; p = align16(p + (size_t)OUT_F * IN_F * sizeof(short));
    unsigned short* wl_T    = (unsigned short*)p; p = align16(p + (size_t)OUT_F * IN_F * sizeof(short));
    int*            offsets = (int*)p;            p = align16(p + (size_t)n_nodes * sizeof(int));
    int*            deg     = (int*)p;            p = align16(p + (size_t)n_nodes * sizeof(int));
    int*            bsums   = (int*)p;            p = align16(p + (size_t)256 * sizeof(int));
    unsigned int*   csr_cv  = (unsigned int*)p;   p = align16(p + (size_t)n_edges * sizeof(unsigned int));
    size_t needed = (size_t)(p - (char*)d_ws);

    const int gemm_blocks = (n_nodes + BM - 1) / BM;
    const int eb = (n_edges + 255) / 256;

    if (ws_size >= needed && scan_blocks <= 256 && n_nodes <= 65536) {
        unsigned short* support_bf = (unsigned short*)supp_raw;
        // Stage 0 + 1: W split, then MFMA GEMM (bf16 output)
        gcn_wsplit_kernel<<<(OUT_F * IN_F / 4) / 256, 256, 0, stream>>>(w, wh_T, wl_T);
        gcn_gemm_mfma_kernel<<<gemm_blocks, 256, 0, stream>>>(x, wh_T, wl_T,
                                                              support_bf, n_nodes);
        // Stage 2: CSR build
        hipMemsetAsync(deg, 0, (size_t)n_nodes * sizeof(int), stream);
        gcn_hist_kernel<<<eb, 256, 0, stream>>>(rows, deg, n_edges);
        gcn_scan1_kernel<<<scan_blocks, 256, 0, stream>>>(deg, offsets, bsums, n_nodes);
        gcn_scan2_kernel<<<1, 256, 0, stream>>>(bsums, scan_blocks);
        gcn_scan3_kernel<<<scan_blocks, 256, 0, stream>>>(offsets, bsums, n_nodes);
        gcn_fill_kernel<<<eb, 256, 0, stream>>>(rows, cols, vals, offsets,
                                                csr_cv, n_edges);
        // Stage 3: atomic-free accumulate + fused ReLU
        int gb = (n_nodes + 3) / 4;
        gcn_gather_kernel<<<gb, 256, 0, stream>>>(support_bf, offsets,
                                                  csr_cv, out, n_nodes);
    } else {
        // fallback: VALU GEMM (f32 support) + atomic scatter
        float* support = (float*)supp_raw;
        gcn_gemm_valu_kernel<<<gemm_blocks, 256, 0, stream>>>(x, w, support, n_nodes);
        hipMemsetAsync(d_out, 0, (size_t)out_size * sizeof(float), stream);
        long long total = (long long)n_edges * (OUT_F / 4);
        int sc_blocks = (int)((total + 255) / 256);
        gcn_scatter_kernel<<<sc_blocks, 256, 0, stream>>>(support, vals, rows, cols,
                                                          out, n_edges);
        int n4 = out_size / 4;
        gcn_relu_kernel<<<(n4 + 255) / 256, 256, 0, stream>>>(out, n4);
    }
}